// Round 2
// baseline (147.599 us; speedup 1.0000x reference)
//
#include <hip/hip_runtime.h>

#define NB      16
#define T_IN    2048
#define OUT_LEN 4096
#define D       384
#define D4      (D / 4)   // 96 float4 per row

// ---------------------------------------------------------------------------
// Kernel 1: per-batch inclusive cumsum of repeat_count (2048 int32/batch).
// One block per batch, 256 threads x 8 elements. Also emits seq_len (= last
// cumsum value) as FLOAT into the tail of d_out (output 1 of the tuple).
// ---------------------------------------------------------------------------
__global__ __launch_bounds__(256) void cumsum_kernel(const int* __restrict__ r,
                                                     int* __restrict__ cum,
                                                     float* __restrict__ seqlen_out) {
    const int b   = blockIdx.x;
    const int tid = threadIdx.x;
    const int4* rb = (const int4*)(r + b * T_IN);
    int4*       cb = (int4*)(cum + b * T_IN);

    int4 v0 = rb[tid * 2];
    int4 v1 = rb[tid * 2 + 1];
    int v[8] = {v0.x, v0.y, v0.z, v0.w, v1.x, v1.y, v1.z, v1.w};

    int s = 0;
#pragma unroll
    for (int i = 0; i < 8; ++i) { s += v[i]; v[i] = s; }

    // inclusive wave scan (wave = 64) of per-thread totals
    const int lane = tid & 63;
    const int wid  = tid >> 6;
    int pre = s;
#pragma unroll
    for (int off = 1; off < 64; off <<= 1) {
        int up = __shfl_up(pre, off, 64);
        if (lane >= off) pre += up;
    }

    __shared__ int wsum[4];
    if (lane == 63) wsum[wid] = pre;
    __syncthreads();

    int excl = pre - s;               // exclusive prefix within wave
    for (int w = 0; w < wid; ++w) excl += wsum[w];

#pragma unroll
    for (int i = 0; i < 8; ++i) v[i] += excl;

    cb[tid * 2]     = make_int4(v[0], v[1], v[2], v[3]);
    cb[tid * 2 + 1] = make_int4(v[4], v[5], v[6], v[7]);

    if (tid == 255) seqlen_out[b] = (float)v[7];
}

// ---------------------------------------------------------------------------
// Kernel 2: idx[b][t] = searchsorted(cum[b], t, 'right') clipped, or -1 when
// t >= seq_len (row must be zeroed). 65536 binary searches over L2-resident
// cum arrays (128 KB total).
// ---------------------------------------------------------------------------
__global__ __launch_bounds__(256) void search_kernel(const int* __restrict__ cum,
                                                     int* __restrict__ idx) {
    const int g = blockIdx.x * 256 + threadIdx.x;
    if (g >= NB * OUT_LEN) return;
    const int b = g >> 12;               // g / OUT_LEN
    const int t = g & (OUT_LEN - 1);
    const int* cb = cum + b * T_IN;
    const int seq = cb[T_IN - 1];

    int res = -1;
    if (t < seq) {
        int lo = 0, hi = T_IN;
        while (lo < hi) {
            int mid = (lo + hi) >> 1;
            if (cb[mid] <= t) lo = mid + 1; else hi = mid;
        }
        res = lo < (T_IN - 1) ? lo : (T_IN - 1);
    }
    idx[g] = res;
}

// ---------------------------------------------------------------------------
// Kernel 3: row gather. Each block = 8 output rows x 96 float4 = 768 float4
// = 3 chunks of 256 threads. Fully coalesced writes across the whole
// (B, OUT_LEN, D) output. idx < 0 -> zeros (valid-mask + 0xAA poison).
// ---------------------------------------------------------------------------
__global__ __launch_bounds__(256) void gather_kernel(const float4* __restrict__ x,
                                                     const int* __restrict__ idx,
                                                     float4* __restrict__ out) {
    const unsigned row0  = blockIdx.x * 8u;               // 8 rows per block
    const unsigned base  = row0 * D4;                     // first float4 of block
    const unsigned b     = row0 >> 12;                    // row0 / OUT_LEN (8 | OUT_LEN)
    const float4*  xb    = x + (size_t)b * T_IN * D4;

#pragma unroll
    for (int k = 0; k < 3; ++k) {
        const unsigned local = threadIdx.x + k * 256u;    // 0..767
        const unsigned rloc  = local / D4;                // compile-time-96 division
        const unsigned d     = local - rloc * D4;
        const int irow = idx[row0 + rloc];
        float4 val = make_float4(0.f, 0.f, 0.f, 0.f);
        if (irow >= 0) val = xb[(unsigned)irow * D4 + d];
        out[base + local] = val;
    }
}

extern "C" void kernel_launch(void* const* d_in, const int* in_sizes, int n_in,
                              void* d_out, int out_size, void* d_ws, size_t ws_size,
                              hipStream_t stream) {
    const float* x  = (const float*)d_in[0];
    const int*   rc = (const int*)d_in[1];
    // d_in[2] = output_max_seq_len scalar (4096), compiled in.

    float* out        = (float*)d_out;
    float* seqlen_out = out + (size_t)NB * OUT_LEN * D;  // tail: output 1

    int* cum = (int*)d_ws;                 // NB*T_IN ints    = 128 KB
    int* idx = cum + NB * T_IN;            // NB*OUT_LEN ints = 256 KB

    cumsum_kernel<<<NB, 256, 0, stream>>>(rc, cum, seqlen_out);

    const int n_pos = NB * OUT_LEN;                        // 65536
    search_kernel<<<n_pos / 256, 256, 0, stream>>>(cum, idx);

    const unsigned n_rows = (unsigned)NB * OUT_LEN;        // 65536 rows
    gather_kernel<<<n_rows / 8, 256, 0, stream>>>((const float4*)x, idx,
                                                  (float4*)out);
}